// Round 1
// baseline (21955.705 us; speedup 1.0000x reference)
//
#include <hip/hip_runtime.h>
#include <math.h>

namespace {

constexpr int Bb = 1024;
constexpr int Tn = 64;
constexpr int Dn = 8;
constexpr int Hn = 64;
constexpr int Wn = 128;
constexpr int BT = 4;    // batch rows per block
constexpr int NT = 512;  // threads per block

// Tsit5 tableau
constexpr float A21 = 0.161f;
constexpr float A31 = -0.008480655492356989f, A32 = 0.335480655492357f;
constexpr float A41 = 2.8971530571054935f, A42 = -6.359448489975075f, A43 = 4.3622954328695815f;
constexpr float A51 = 5.325864828439257f, A52 = -11.748883564062828f, A53 = 7.4955393428898365f, A54 = -0.09249506636175525f;
constexpr float A61 = 5.86145544294642f, A62 = -12.92096931784711f, A63 = 8.159367898576159f, A64 = -0.071584973281401f, A65 = -0.028269050394068383f;
constexpr float Bc1 = 0.09646076681806523f, Bc2 = 0.01f, Bc3 = 0.4798896504144996f;
constexpr float Bc4 = 1.379008574103742f, Bc5 = -3.290069515436081f, Bc6 = 2.324710524099774f;

__device__ inline float softplus_f(float x) {
  // log1p(exp(x)) stable form == jnp.logaddexp(x, 0)
  return fmaxf(x, 0.f) + log1pf(expf(-fabsf(x)));
}
__device__ inline float dot4(float4 w, float4 a) {
  return w.x * a.x + w.y * a.y + w.z * a.z + w.w * a.w;
}

} // namespace

// Persistent per-batch-tile NeuralCDE integrator.
// Block = 512 threads (8 waves), owns 4 batch rows for all 63 Tsit5 steps.
// vf weights register-resident: thread tid holds vw3 row tid (128 f32),
// vw2 quarter-row (32 f32) and vw1 quarter-row (16 f32) for o=tid&127, q=tid>>7.
__global__ __launch_bounds__(NT, 2)
void ncde_kernel(const float* __restrict__ xs,
                 const float* __restrict__ iw1, const float* __restrict__ ib1,
                 const float* __restrict__ iw2, const float* __restrict__ ib2,
                 const float* __restrict__ iw3, const float* __restrict__ ib3,
                 const float* __restrict__ vw1, const float* __restrict__ vb1,
                 const float* __restrict__ vw2, const float* __restrict__ vb2,
                 const float* __restrict__ vw3, const float* __restrict__ vb3,
                 const float* __restrict__ lw,  const float* __restrict__ lb,
                 float* __restrict__ out)
{
  __shared__ float xs_l[BT][Tn * Dn];     // 8 KB: this block's control path
  __shared__ float y_l[BT][Hn];           // current state
  __shared__ float ys_l[BT][Hn];          // stage input
  __shared__ float K_l[6][BT][Hn];        // dt-scaled stage slopes
  __shared__ float h1_l[BT][Wn];
  __shared__ float h2_l[BT][Wn];
  __shared__ float part_l[4][BT][Wn];     // k-split partial sums
  __shared__ float dxs_l[BT][Dn];         // xs[t+1]-xs[t]  (== dt * dX/dt)
  __shared__ float lw_l[Hn];

  const int tid = threadIdx.x;
  const int oo  = tid & (Wn - 1);
  const int q   = tid >> 7;
  const int b0  = blockIdx.x * BT;

  // ---- weights -> registers ----
  float4 w3r[32];
  #pragma unroll
  for (int i = 0; i < 32; ++i) w3r[i] = ((const float4*)(vw3 + tid * Wn))[i];
  float4 w2r[8];
  #pragma unroll
  for (int i = 0; i < 8; ++i) w2r[i] = ((const float4*)(vw2 + oo * Wn + q * 32))[i];
  float4 w1r[4];
  #pragma unroll
  for (int i = 0; i < 4; ++i) w1r[i] = ((const float4*)(vw1 + oo * Hn + q * 16))[i];
  const float b3r = vb3[tid];
  const float b2r = vb2[oo];
  const float b1r = vb1[oo];
  const float lb0 = lb[0];

  // ---- stage this block's xs rows (coalesced, 512 x float4) ----
  ((float4*)&xs_l[0][0])[tid] = ((const float4*)(xs + b0 * Tn * Dn))[tid];
  if (tid < Hn) lw_l[tid] = lw[tid];
  __syncthreads();

  // ---- initial MLP (relu, relu, identity): y0 = mlp(xs[:,0]) ----
  {
    const int b = q;
    float acc = ib1[oo];
    #pragma unroll
    for (int k = 0; k < Dn; ++k) acc += iw1[oo * Dn + k] * xs_l[b][k];
    h1_l[b][oo] = fmaxf(acc, 0.f);
  }
  __syncthreads();
  {
    const int b = q;
    float acc = ib2[oo];
    const float4* wrow = (const float4*)(iw2 + oo * Wn);
    #pragma unroll
    for (int k4 = 0; k4 < Wn / 4; ++k4)
      acc += dot4(wrow[k4], *(const float4*)&h1_l[b][k4 * 4]);
    h2_l[b][oo] = fmaxf(acc, 0.f);
  }
  __syncthreads();
  if (tid < BT * Hn) {
    const int b = tid >> 6, h = tid & (Hn - 1);
    float acc = ib3[h];
    const float4* wrow = (const float4*)(iw3 + h * Wn);
    #pragma unroll
    for (int k4 = 0; k4 < Wn / 4; ++k4)
      acc += dot4(wrow[k4], *(const float4*)&h2_l[b][k4 * 4]);
    y_l[b][h] = acc;
  }
  __syncthreads();

  auto readout = [&](int t) {
    if (tid < BT * Hn) {
      const int wv = tid >> 6, h = tid & (Hn - 1);
      float p = lw_l[h] * y_l[wv][h];
      #pragma unroll
      for (int off = 32; off > 0; off >>= 1) p += __shfl_xor(p, off, 64);
      if (h == 0) out[(b0 + wv) * Tn + t] = 1.f / (1.f + expf(-(p + lb0)));
    }
  };
  readout(0);

  // ---- 63 Tsit5 steps ----
  for (int t = 0; t < Tn - 1; ++t) {
    if (tid < BT * Hn) {
      const int b = tid >> 6, h = tid & (Hn - 1);
      ys_l[b][h] = y_l[b][h];               // stage-1 input is y
    } else if (tid < BT * Hn + BT * Dn) {
      const int r = tid - BT * Hn;
      const int b = r >> 3, d = r & 7;
      // K_i = dt * vf = f(ys) . (xs[t+1]-xs[t])  (dt folds exactly)
      dxs_l[b][d] = xs_l[b][(t + 1) * Dn + d] - xs_l[b][t * Dn + d];
    }
    __syncthreads();

    #pragma unroll
    for (int s = 0; s < 6; ++s) {
      // ---- vf layer 1: [4,64] -> [4,128], k-split 4 ways ----
      {
        float a[BT] = {0, 0, 0, 0};
        #pragma unroll
        for (int j4 = 0; j4 < 4; ++j4) {
          const float4 w = w1r[j4];
          #pragma unroll
          for (int b = 0; b < BT; ++b)
            a[b] += dot4(w, *(const float4*)&ys_l[b][q * 16 + j4 * 4]);
        }
        #pragma unroll
        for (int b = 0; b < BT; ++b) part_l[q][b][oo] = a[b];
      }
      __syncthreads();
      {
        const int b = q;
        float acc = b1r;
        #pragma unroll
        for (int j = 0; j < 4; ++j) acc += part_l[j][b][oo];
        h1_l[b][oo] = softplus_f(acc);
      }
      __syncthreads();
      // ---- vf layer 2: [4,128] -> [4,128], k-split 4 ways ----
      {
        float a[BT] = {0, 0, 0, 0};
        #pragma unroll
        for (int j4 = 0; j4 < 8; ++j4) {
          const float4 w = w2r[j4];
          #pragma unroll
          for (int b = 0; b < BT; ++b)
            a[b] += dot4(w, *(const float4*)&h1_l[b][q * 32 + j4 * 4]);
        }
        #pragma unroll
        for (int b = 0; b < BT; ++b) part_l[q][b][oo] = a[b];
      }
      __syncthreads();
      {
        const int b = q;
        float acc = b2r;
        #pragma unroll
        for (int j = 0; j < 4; ++j) acc += part_l[j][b][oo];
        h2_l[b][oo] = softplus_f(acc);
      }
      __syncthreads();
      // ---- vf layer 3 [4,128]->[4,512], tanh, einsum with dx ----
      {
        float a[BT] = {0, 0, 0, 0};
        #pragma unroll
        for (int k4 = 0; k4 < 32; ++k4) {
          const float4 w = w3r[k4];
          #pragma unroll
          for (int b = 0; b < BT; ++b)
            a[b] += dot4(w, *(const float4*)&h2_l[b][k4 * 4]);
        }
        const int d = tid & 7, h = tid >> 3;   // o3 = h*8+d
        #pragma unroll
        for (int b = 0; b < BT; ++b) {
          float p = tanhf(a[b] + b3r) * dxs_l[b][d];
          p += __shfl_xor(p, 1, 64);
          p += __shfl_xor(p, 2, 64);
          p += __shfl_xor(p, 4, 64);
          if (d == 0) K_l[s][b][h] = p;
        }
      }
      __syncthreads();
      // ---- stage prep / final update ----
      if (tid < BT * Hn) {
        const int b = tid >> 6, h = tid & (Hn - 1);
        float v = y_l[b][h];
        if (s == 0)      v += A21 * K_l[0][b][h];
        else if (s == 1) v += A31 * K_l[0][b][h] + A32 * K_l[1][b][h];
        else if (s == 2) v += A41 * K_l[0][b][h] + A42 * K_l[1][b][h] + A43 * K_l[2][b][h];
        else if (s == 3) v += A51 * K_l[0][b][h] + A52 * K_l[1][b][h] + A53 * K_l[2][b][h] + A54 * K_l[3][b][h];
        else if (s == 4) v += A61 * K_l[0][b][h] + A62 * K_l[1][b][h] + A63 * K_l[2][b][h] + A64 * K_l[3][b][h] + A65 * K_l[4][b][h];
        else             v += Bc1 * K_l[0][b][h] + Bc2 * K_l[1][b][h] + Bc3 * K_l[2][b][h]
                            + Bc4 * K_l[3][b][h] + Bc5 * K_l[4][b][h] + Bc6 * K_l[5][b][h];
        if (s < 5) ys_l[b][h] = v; else y_l[b][h] = v;
      }
      __syncthreads();
    }
    readout(t + 1);
  }
}

extern "C" void kernel_launch(void* const* d_in, const int* in_sizes, int n_in,
                              void* d_out, int out_size, void* d_ws, size_t ws_size,
                              hipStream_t stream) {
  const float* xs  = (const float*)d_in[1];
  const float* iw1 = (const float*)d_in[2];
  const float* ib1 = (const float*)d_in[3];
  const float* iw2 = (const float*)d_in[4];
  const float* ib2 = (const float*)d_in[5];
  const float* iw3 = (const float*)d_in[6];
  const float* ib3 = (const float*)d_in[7];
  const float* vw1 = (const float*)d_in[8];
  const float* vb1 = (const float*)d_in[9];
  const float* vw2 = (const float*)d_in[10];
  const float* vb2 = (const float*)d_in[11];
  const float* vw3 = (const float*)d_in[12];
  const float* vb3 = (const float*)d_in[13];
  const float* lw  = (const float*)d_in[14];
  const float* lb  = (const float*)d_in[15];
  float* out = (float*)d_out;

  ncde_kernel<<<Bb / BT, NT, 0, stream>>>(xs, iw1, ib1, iw2, ib2, iw3, ib3,
                                          vw1, vb1, vw2, vb2, vw3, vb3, lw, lb, out);
}

// Round 2
// 21639.876 us; speedup vs baseline: 1.0146x; 1.0146x over previous
//
#include <hip/hip_runtime.h>
#include <math.h>

namespace {

constexpr int Bb = 1024;
constexpr int Tn = 64;
constexpr int Dn = 8;
constexpr int Hn = 64;
constexpr int Wn = 128;
constexpr int BT = 4;    // batch rows per block
constexpr int NT = 512;  // threads per block

// Tsit5 tableau
constexpr float A21 = 0.161f;
constexpr float A31 = -0.008480655492356989f, A32 = 0.335480655492357f;
constexpr float A41 = 2.8971530571054935f, A42 = -6.359448489975075f, A43 = 4.3622954328695815f;
constexpr float A51 = 5.325864828439257f, A52 = -11.748883564062828f, A53 = 7.4955393428898365f, A54 = -0.09249506636175525f;
constexpr float A61 = 5.86145544294642f, A62 = -12.92096931784711f, A63 = 8.159367898576159f, A64 = -0.071584973281401f, A65 = -0.028269050394068383f;
constexpr float Bc1 = 0.09646076681806523f, Bc2 = 0.01f, Bc3 = 0.4798896504144996f;
constexpr float Bc4 = 1.379008574103742f, Bc5 = -3.290069515436081f, Bc6 = 2.324710524099774f;

__device__ inline float softplus_f(float x) {
  return fmaxf(x, 0.f) + log1pf(expf(-fabsf(x)));
}
__device__ inline float dot4(float4 w, float4 a) {
  return w.x * a.x + w.y * a.y + w.z * a.z + w.w * a.w;
}

} // namespace

// Persistent per-batch-tile NeuralCDE integrator.
// Block = 512 threads (8 waves), owns 4 batch rows for all 63 Tsit5 steps.
// vf weights register-resident: thread tid holds vw3 row tid (128 f32),
// vw2 quarter-row (32 f32) and vw1 quarter-row (16 f32) for o=tid&127, q=tid>>7.
// waves_per_eu(2,2): pin exactly 2 waves/SIMD -> 256-VGPR budget so the
// 176 weight registers stay resident (R1 spilled at the default 128 cap:
// 39.8 GB of scratch FETCH per dispatch).
__attribute__((amdgpu_waves_per_eu(2, 2)))
__global__ __launch_bounds__(NT)
void ncde_kernel(const float* __restrict__ xs,
                 const float* __restrict__ iw1, const float* __restrict__ ib1,
                 const float* __restrict__ iw2, const float* __restrict__ ib2,
                 const float* __restrict__ iw3, const float* __restrict__ ib3,
                 const float* __restrict__ vw1, const float* __restrict__ vb1,
                 const float* __restrict__ vw2, const float* __restrict__ vb2,
                 const float* __restrict__ vw3, const float* __restrict__ vb3,
                 const float* __restrict__ lw,  const float* __restrict__ lb,
                 float* __restrict__ out)
{
  __shared__ float xs_l[BT][Tn * Dn];     // 8 KB: this block's control path
  __shared__ float y_l[BT][Hn];           // current state
  __shared__ float ys_l[BT][Hn];          // stage input
  __shared__ float K_l[6][BT][Hn];        // dt-scaled stage slopes
  __shared__ float h1_l[BT][Wn];
  __shared__ float h2_l[BT][Wn];
  __shared__ float part_l[4][BT][Wn];     // k-split partial sums
  __shared__ float dxs_l[BT][Dn];         // xs[t+1]-xs[t]  (== dt * dX/dt)
  __shared__ float lw_l[Hn];

  const int tid = threadIdx.x;
  const int oo  = tid & (Wn - 1);
  const int q   = tid >> 7;
  const int b0  = blockIdx.x * BT;

  // ---- weights -> registers (scalar arrays: no quad-alignment pressure) ----
  float w3r[128];
  #pragma unroll
  for (int i = 0; i < 128; ++i) w3r[i] = vw3[tid * Wn + i];
  float w2r[32];
  #pragma unroll
  for (int i = 0; i < 32; ++i) w2r[i] = vw2[oo * Wn + q * 32 + i];
  float w1r[16];
  #pragma unroll
  for (int i = 0; i < 16; ++i) w1r[i] = vw1[oo * Hn + q * 16 + i];
  const float b3r = vb3[tid];
  const float b2r = vb2[oo];
  const float b1r = vb1[oo];
  const float lb0 = lb[0];

  // ---- stage this block's xs rows (coalesced, 512 x float4) ----
  ((float4*)&xs_l[0][0])[tid] = ((const float4*)(xs + b0 * Tn * Dn))[tid];
  if (tid < Hn) lw_l[tid] = lw[tid];
  __syncthreads();

  // ---- initial MLP (relu, relu, identity): y0 = mlp(xs[:,0]) ----
  {
    const int b = q;
    float acc = ib1[oo];
    #pragma unroll
    for (int k = 0; k < Dn; ++k) acc += iw1[oo * Dn + k] * xs_l[b][k];
    h1_l[b][oo] = fmaxf(acc, 0.f);
  }
  __syncthreads();
  {
    const int b = q;
    float acc = ib2[oo];
    const float4* wrow = (const float4*)(iw2 + oo * Wn);
    #pragma unroll
    for (int k4 = 0; k4 < Wn / 4; ++k4)
      acc += dot4(wrow[k4], *(const float4*)&h1_l[b][k4 * 4]);
    h2_l[b][oo] = fmaxf(acc, 0.f);
  }
  __syncthreads();
  if (tid < BT * Hn) {
    const int b = tid >> 6, h = tid & (Hn - 1);
    float acc = ib3[h];
    const float4* wrow = (const float4*)(iw3 + h * Wn);
    #pragma unroll
    for (int k4 = 0; k4 < Wn / 4; ++k4)
      acc += dot4(wrow[k4], *(const float4*)&h2_l[b][k4 * 4]);
    y_l[b][h] = acc;
  }
  __syncthreads();

  auto readout = [&](int t) {
    if (tid < BT * Hn) {
      const int wv = tid >> 6, h = tid & (Hn - 1);
      float p = lw_l[h] * y_l[wv][h];
      #pragma unroll
      for (int off = 32; off > 0; off >>= 1) p += __shfl_xor(p, off, 64);
      if (h == 0) out[(b0 + wv) * Tn + t] = 1.f / (1.f + expf(-(p + lb0)));
    }
  };
  readout(0);

  // ---- 63 Tsit5 steps ----
  for (int t = 0; t < Tn - 1; ++t) {
    if (tid < BT * Hn) {
      const int b = tid >> 6, h = tid & (Hn - 1);
      ys_l[b][h] = y_l[b][h];               // stage-1 input is y
    } else if (tid < BT * Hn + BT * Dn) {
      const int r = tid - BT * Hn;
      const int b = r >> 3, d = r & 7;
      // K_i = dt * vf = f(ys) . (xs[t+1]-xs[t])  (dt folds exactly)
      dxs_l[b][d] = xs_l[b][(t + 1) * Dn + d] - xs_l[b][t * Dn + d];
    }
    __syncthreads();

    #pragma unroll
    for (int s = 0; s < 6; ++s) {
      // ---- vf layer 1: [4,64] -> [4,128], k-split 4 ways ----
      {
        float a[BT] = {0, 0, 0, 0};
        #pragma unroll
        for (int j4 = 0; j4 < 4; ++j4) {
          #pragma unroll
          for (int b = 0; b < BT; ++b) {
            const float4 av = *(const float4*)&ys_l[b][q * 16 + j4 * 4];
            a[b] += w1r[j4 * 4 + 0] * av.x + w1r[j4 * 4 + 1] * av.y
                  + w1r[j4 * 4 + 2] * av.z + w1r[j4 * 4 + 3] * av.w;
          }
        }
        #pragma unroll
        for (int b = 0; b < BT; ++b) part_l[q][b][oo] = a[b];
      }
      __syncthreads();
      {
        const int b = q;
        float acc = b1r;
        #pragma unroll
        for (int j = 0; j < 4; ++j) acc += part_l[j][b][oo];
        h1_l[b][oo] = softplus_f(acc);
      }
      __syncthreads();
      // ---- vf layer 2: [4,128] -> [4,128], k-split 4 ways ----
      {
        float a[BT] = {0, 0, 0, 0};
        #pragma unroll
        for (int j4 = 0; j4 < 8; ++j4) {
          #pragma unroll
          for (int b = 0; b < BT; ++b) {
            const float4 av = *(const float4*)&h1_l[b][q * 32 + j4 * 4];
            a[b] += w2r[j4 * 4 + 0] * av.x + w2r[j4 * 4 + 1] * av.y
                  + w2r[j4 * 4 + 2] * av.z + w2r[j4 * 4 + 3] * av.w;
          }
        }
        #pragma unroll
        for (int b = 0; b < BT; ++b) part_l[q][b][oo] = a[b];
      }
      __syncthreads();
      {
        const int b = q;
        float acc = b2r;
        #pragma unroll
        for (int j = 0; j < 4; ++j) acc += part_l[j][b][oo];
        h2_l[b][oo] = softplus_f(acc);
      }
      __syncthreads();
      // ---- vf layer 3 [4,128]->[4,512], tanh, einsum with dx ----
      {
        float a[BT] = {0, 0, 0, 0};
        #pragma unroll
        for (int k4 = 0; k4 < 32; ++k4) {
          #pragma unroll
          for (int b = 0; b < BT; ++b) {
            const float4 av = *(const float4*)&h2_l[b][k4 * 4];
            a[b] += w3r[k4 * 4 + 0] * av.x + w3r[k4 * 4 + 1] * av.y
                  + w3r[k4 * 4 + 2] * av.z + w3r[k4 * 4 + 3] * av.w;
          }
        }
        const int d = tid & 7, h = tid >> 3;   // o3 = h*8+d
        #pragma unroll
        for (int b = 0; b < BT; ++b) {
          float p = tanhf(a[b] + b3r) * dxs_l[b][d];
          p += __shfl_xor(p, 1, 64);
          p += __shfl_xor(p, 2, 64);
          p += __shfl_xor(p, 4, 64);
          if (d == 0) K_l[s][b][h] = p;
        }
      }
      __syncthreads();
      // ---- stage prep / final update ----
      if (tid < BT * Hn) {
        const int b = tid >> 6, h = tid & (Hn - 1);
        float v = y_l[b][h];
        if (s == 0)      v += A21 * K_l[0][b][h];
        else if (s == 1) v += A31 * K_l[0][b][h] + A32 * K_l[1][b][h];
        else if (s == 2) v += A41 * K_l[0][b][h] + A42 * K_l[1][b][h] + A43 * K_l[2][b][h];
        else if (s == 3) v += A51 * K_l[0][b][h] + A52 * K_l[1][b][h] + A53 * K_l[2][b][h] + A54 * K_l[3][b][h];
        else if (s == 4) v += A61 * K_l[0][b][h] + A62 * K_l[1][b][h] + A63 * K_l[2][b][h] + A64 * K_l[3][b][h] + A65 * K_l[4][b][h];
        else             v += Bc1 * K_l[0][b][h] + Bc2 * K_l[1][b][h] + Bc3 * K_l[2][b][h]
                            + Bc4 * K_l[3][b][h] + Bc5 * K_l[4][b][h] + Bc6 * K_l[5][b][h];
        if (s < 5) ys_l[b][h] = v; else y_l[b][h] = v;
      }
      __syncthreads();
    }
    readout(t + 1);
  }
}

extern "C" void kernel_launch(void* const* d_in, const int* in_sizes, int n_in,
                              void* d_out, int out_size, void* d_ws, size_t ws_size,
                              hipStream_t stream) {
  const float* xs  = (const float*)d_in[1];
  const float* iw1 = (const float*)d_in[2];
  const float* ib1 = (const float*)d_in[3];
  const float* iw2 = (const float*)d_in[4];
  const float* ib2 = (const float*)d_in[5];
  const float* iw3 = (const float*)d_in[6];
  const float* ib3 = (const float*)d_in[7];
  const float* vw1 = (const float*)d_in[8];
  const float* vb1 = (const float*)d_in[9];
  const float* vw2 = (const float*)d_in[10];
  const float* vb2 = (const float*)d_in[11];
  const float* vw3 = (const float*)d_in[12];
  const float* vb3 = (const float*)d_in[13];
  const float* lw  = (const float*)d_in[14];
  const float* lb  = (const float*)d_in[15];
  float* out = (float*)d_out;

  ncde_kernel<<<Bb / BT, NT, 0, stream>>>(xs, iw1, ib1, iw2, ib2, iw3, ib3,
                                          vw1, vb1, vw2, vb2, vw3, vb3, lw, lb, out);
}